// Round 2
// baseline (531.501 us; speedup 1.0000x reference)
//
#include <hip/hip_runtime.h>
#include <hip/hip_bf16.h>

#define M_TOK 2048
#define KDIM 2048
#define NDIM 1408
#define NEXP 8
#define RROWS (M_TOK * 2)
#define CAP 1024

typedef __attribute__((ext_vector_type(8))) short short8;
typedef __attribute__((ext_vector_type(4))) float f32x4;

__device__ __forceinline__ unsigned short bf16rn(float f) {
    unsigned int u = __builtin_bit_cast(unsigned int, f);
    u += 0x7FFFu + ((u >> 16) & 1u);
    return (unsigned short)(u >> 16);
}
__device__ __forceinline__ unsigned int pk2(float a, float b) {
    return (unsigned int)bf16rn(a) | ((unsigned int)bf16rn(b) << 16);
}
// packed fp32x2 -> bf16x2 (RNE), compiler-scheduled (m240: don't hand-asm this)
__device__ __forceinline__ unsigned int cvtpk(float a, float b) {
    __hip_bfloat162 h = __float22bfloat162_rn(make_float2(a, b));
    unsigned int u;
    __builtin_memcpy(&u, &h, 4);
    return u;
}

// async global->LDS, 16 B per lane; LDS dest wave-uniform base + lane*16
__device__ __forceinline__ void glds16(const void* g, void* l) {
    __builtin_amdgcn_global_load_lds(
        (const __attribute__((address_space(1))) unsigned int*)g,
        (__attribute__((address_space(3))) unsigned int*)l, 16, 0, 0);
}

// ---------------- routing + dispatch (fp32 -> bf16 row copy) ----------------
__global__ void k_route(const float* __restrict__ h, const int* __restrict__ idx,
                        int* __restrict__ cnt, int* __restrict__ slot_of,
                        unsigned short* __restrict__ bufA) {
    int r = blockIdx.x;
    __shared__ int s_ep;
    if (threadIdx.x == 0) {
        int e = idx[r];
        int p = atomicAdd(&cnt[e], 1);
        int ep = e * CAP + p;
        slot_of[r] = ep;
        s_ep = ep;
    }
    __syncthreads();
    int ep = s_ep;
    const float4* src = (const float4*)(h + (size_t)(r >> 1) * KDIM) + threadIdx.x * 2;
    float4 a = src[0], b = src[1];
    uint4 o;
    o.x = pk2(a.x, a.y); o.y = pk2(a.z, a.w);
    o.z = pk2(b.x, b.y); o.w = pk2(b.z, b.w);
    *((uint4*)(bufA + (size_t)ep * KDIM) + threadIdx.x) = o;
}

// ---------------- GEMM1: g,u = A @ W^T ; h = silu(min(g,10)) * clip(u) ------
// fp32 weights converted to bf16 in-kernel (reg-staged, swizzled ds_write).
// flat grid, XCD-aware: xcd = expert; all 11 n-blocks of an (m,e) pair on one XCD
__global__ __launch_bounds__(256, 2)
void k_gemm1(const unsigned short* __restrict__ bufA,
             const float* __restrict__ gw,
             const float* __restrict__ uw,
             const int* __restrict__ cnt, unsigned short* __restrict__ hbuf) {
    const int f = blockIdx.x;
    const int e = f & 7;
    const int t = f >> 3;            // 0..87
    const int n_blk = t % 11;
    const int m_blk = t / 11;        // 0..7
    const int m0 = m_blk * 128;
    if (m0 >= cnt[e]) return;
    const int n0 = n_blk * 128;

    const unsigned short* A = bufA + (size_t)e * CAP * KDIM;
    const float* G = gw + (size_t)e * NDIM * KDIM;
    const float* U = uw + (size_t)e * NDIM * KDIM;

    __shared__ unsigned short sA[128 * 64];
    __shared__ unsigned short sG[128 * 64];
    __shared__ unsigned short sU[128 * 64];

    const int tid = threadIdx.x;
    const int lane = tid & 63;
    const int wave = tid >> 6;
    const int wm = (wave >> 1) * 64, wn = (wave & 1) * 64;
    const int q = lane >> 4, l15 = lane & 15;
    // DMA source swizzle for A: lane covers (row_in_seg = lane>>3, cb = (lane&7)^(row&7))
    const int sr = lane >> 3;
    const int scb = (lane & 7) ^ (sr & 7);
    const int xi = l15 & 7;                 // reader xor key
    const int cbl0 = (q ^ xi) * 8;          // kh=0 LDS col offset (shorts)
    const int cbl1 = ((4 + q) ^ xi) * 8;    // kh=1

    // weight reg-staging geometry: thread owns 32 contiguous fp32 of one row
    const int wrow = tid >> 1;              // 0..127 (weight tile row)
    const int wh = tid & 1;                 // which 32-col half
    const int wx = wrow & 7;                // writer xor key (matches reader)
    const float* gsrc0 = G + (size_t)(n0 + wrow) * KDIM + wh * 32;
    const float* usrc0 = U + (size_t)(n0 + wrow) * KDIM + wh * 32;
    unsigned short* wdG = &sG[wrow * 64];
    unsigned short* wdU = &sU[wrow * 64];

    f32x4 accG[4][4] = {};
    f32x4 accU[4][4] = {};

    for (int k0 = 0; k0 < KDIM; k0 += 64) {
        // issue weight loads early (global only — safe before barrier)
        const float4* gs = (const float4*)(gsrc0 + k0);
        const float4* us = (const float4*)(usrc0 + k0);
        float4 gv[8], uv[8];
#pragma unroll
        for (int i = 0; i < 8; i++) gv[i] = gs[i];
#pragma unroll
        for (int i = 0; i < 8; i++) uv[i] = us[i];

        __syncthreads();                    // prev iter's LDS reads complete
#pragma unroll
        for (int c = 0; c < 4; c++) {
            int seg = wave * 4 + c;         // wave-uniform
            int row = seg * 8 + sr;
            glds16(A + (size_t)(m0 + row) * KDIM + k0 + scb * 8, &sA[seg * 512]);
        }
        // convert + swizzled store: granule cb lands at position cb^(row&7)
#pragma unroll
        for (int g = 0; g < 4; g++) {
            uint4 o;
            o.x = cvtpk(gv[2 * g].x, gv[2 * g].y);
            o.y = cvtpk(gv[2 * g].z, gv[2 * g].w);
            o.z = cvtpk(gv[2 * g + 1].x, gv[2 * g + 1].y);
            o.w = cvtpk(gv[2 * g + 1].z, gv[2 * g + 1].w);
            *(uint4*)(wdG + (((wh * 4 + g) ^ wx) * 8)) = o;
        }
#pragma unroll
        for (int g = 0; g < 4; g++) {
            uint4 o;
            o.x = cvtpk(uv[2 * g].x, uv[2 * g].y);
            o.y = cvtpk(uv[2 * g].z, uv[2 * g].w);
            o.z = cvtpk(uv[2 * g + 1].x, uv[2 * g + 1].y);
            o.w = cvtpk(uv[2 * g + 1].z, uv[2 * g + 1].w);
            *(uint4*)(wdU + (((wh * 4 + g) ^ wx) * 8)) = o;
        }
        __syncthreads();

#pragma unroll
        for (int kh = 0; kh < 2; kh++) {
            const int co = kh ? cbl1 : cbl0;
            short8 af[4], gf[4], uf[4];
#pragma unroll
            for (int i = 0; i < 4; i++) {
                af[i] = *(const short8*)&sA[(wm + i * 16 + l15) * 64 + co];
                gf[i] = *(const short8*)&sG[(wn + i * 16 + l15) * 64 + co];
                uf[i] = *(const short8*)&sU[(wn + i * 16 + l15) * 64 + co];
            }
#pragma unroll
            for (int i = 0; i < 4; i++)
#pragma unroll
                for (int j = 0; j < 4; j++) {
                    accG[i][j] = __builtin_amdgcn_mfma_f32_16x16x32_bf16(af[i], gf[j], accG[i][j], 0, 0, 0);
                    accU[i][j] = __builtin_amdgcn_mfma_f32_16x16x32_bf16(af[i], uf[j], accU[i][j], 0, 0, 0);
                }
        }
    }

    unsigned short* H = hbuf + (size_t)e * CAP * NDIM;
#pragma unroll
    for (int i = 0; i < 4; i++)
#pragma unroll
        for (int j = 0; j < 4; j++) {
            int col = n0 + wn + j * 16 + l15;
#pragma unroll
            for (int rg = 0; rg < 4; rg++) {
                int row = m0 + wm + i * 16 + q * 4 + rg;
                float g = accG[i][j][rg];
                float u = accU[i][j][rg];
                g = fminf(g, 10.f);
                u = fminf(fmaxf(u, -10.f), 10.f);
                float hv = g / (1.f + __expf(-g)) * u;
                H[(size_t)row * NDIM + col] = bf16rn(hv);
            }
        }
}

// ---------------- GEMM2: d = h @ dw^T -> dbuf (fp32, no atomics) ------------
// fp32 down-weight converted to bf16 in-kernel (reg-staged, swizzled ds_write).
__global__ __launch_bounds__(256, 2)
void k_gemm2(const unsigned short* __restrict__ hbuf,
             const float* __restrict__ dwn, const int* __restrict__ cnt,
             float* __restrict__ dbuf) {
    const int f = blockIdx.x;
    const int e = f & 7;
    const int t = f >> 3;            // 0..127
    const int n_blk = t & 15;
    const int m_blk = t >> 4;        // 0..7
    const int cnt_e = cnt[e];
    const int m0 = m_blk * 128;
    if (m0 >= cnt_e) return;
    const int n0 = n_blk * 128;      // over KDIM

    const unsigned short* A = hbuf + (size_t)e * CAP * NDIM;
    const float* B = dwn + (size_t)e * KDIM * NDIM;

    __shared__ unsigned short sA[128 * 64];
    __shared__ unsigned short sB[128 * 64];

    const int tid = threadIdx.x;
    const int lane = tid & 63;
    const int wave = tid >> 6;
    const int wm = (wave >> 1) * 64, wn = (wave & 1) * 64;
    const int q = lane >> 4, l15 = lane & 15;
    const int sr = lane >> 3;
    const int scb = (lane & 7) ^ (sr & 7);
    const int xi = l15 & 7;
    const int cbl0 = (q ^ xi) * 8;
    const int cbl1 = ((4 + q) ^ xi) * 8;

    const int wrow = tid >> 1;
    const int wh = tid & 1;
    const int wx = wrow & 7;
    const float* bsrc0 = B + (size_t)(n0 + wrow) * NDIM + wh * 32;
    unsigned short* wdB = &sB[wrow * 64];

    f32x4 acc[4][4] = {};

    for (int k0 = 0; k0 < NDIM; k0 += 64) {
        const float4* bs = (const float4*)(bsrc0 + k0);
        float4 bv[8];
#pragma unroll
        for (int i = 0; i < 8; i++) bv[i] = bs[i];

        __syncthreads();
#pragma unroll
        for (int c = 0; c < 4; c++) {
            int seg = wave * 4 + c;
            int row = seg * 8 + sr;
            glds16(A + (size_t)(m0 + row) * NDIM + k0 + scb * 8, &sA[seg * 512]);
        }
#pragma unroll
        for (int g = 0; g < 4; g++) {
            uint4 o;
            o.x = cvtpk(bv[2 * g].x, bv[2 * g].y);
            o.y = cvtpk(bv[2 * g].z, bv[2 * g].w);
            o.z = cvtpk(bv[2 * g + 1].x, bv[2 * g + 1].y);
            o.w = cvtpk(bv[2 * g + 1].z, bv[2 * g + 1].w);
            *(uint4*)(wdB + (((wh * 4 + g) ^ wx) * 8)) = o;
        }
        __syncthreads();

#pragma unroll
        for (int kh = 0; kh < 2; kh++) {
            const int co = kh ? cbl1 : cbl0;
            short8 af[4], bfr[4];
#pragma unroll
            for (int i = 0; i < 4; i++) {
                af[i] = *(const short8*)&sA[(wm + i * 16 + l15) * 64 + co];
                bfr[i] = *(const short8*)&sB[(wn + i * 16 + l15) * 64 + co];
            }
#pragma unroll
            for (int i = 0; i < 4; i++)
#pragma unroll
                for (int j = 0; j < 4; j++)
                    acc[i][j] = __builtin_amdgcn_mfma_f32_16x16x32_bf16(af[i], bfr[j], acc[i][j], 0, 0, 0);
        }
    }

    float* D = dbuf + (size_t)e * CAP * KDIM;
#pragma unroll
    for (int i = 0; i < 4; i++) {
#pragma unroll
        for (int rg = 0; rg < 4; rg++) {
            int row = m0 + wm + i * 16 + q * 4 + rg;
            if (row < cnt_e) {
                float* drow = D + (size_t)row * KDIM + n0 + wn + l15;
#pragma unroll
                for (int j = 0; j < 4; j++)
                    drow[j * 16] = acc[i][j][rg];
            }
        }
    }
}

// ---------------- combine: out[tok] = g0*d[slot0] + g1*d[slot1] -------------
__global__ void k_combine(const float* __restrict__ dbuf, const int* __restrict__ slot_of,
                          const float* __restrict__ gate, float* __restrict__ out) {
    int tk = blockIdx.x;
    int s0 = slot_of[2 * tk], s1 = slot_of[2 * tk + 1];
    float g0 = gate[2 * tk], g1 = gate[2 * tk + 1];
    const float4* r0 = (const float4*)(dbuf + (size_t)s0 * KDIM);
    const float4* r1 = (const float4*)(dbuf + (size_t)s1 * KDIM);
    float4* o = (float4*)(out + (size_t)tk * KDIM);
    int i = threadIdx.x * 2;
#pragma unroll
    for (int c = 0; c < 2; c++) {
        float4 a = r0[i + c], b = r1[i + c];
        float4 v;
        v.x = g0 * a.x + g1 * b.x;
        v.y = g0 * a.y + g1 * b.y;
        v.z = g0 * a.z + g1 * b.z;
        v.w = g0 * a.w + g1 * b.w;
        o[i + c] = v;
    }
}

extern "C" void kernel_launch(void* const* d_in, const int* in_sizes, int n_in,
                              void* d_out, int out_size, void* d_ws, size_t ws_size,
                              hipStream_t stream) {
    const float* flat_h = (const float*)d_in[0];
    const int* flat_idx = (const int*)d_in[1];
    const float* flat_gate = (const float*)d_in[2];
    const float* gw = (const float*)d_in[3];
    const float* uw = (const float*)d_in[4];
    const float* dwn = (const float*)d_in[5];
    float* out = (float*)d_out;

    char* w = (char*)d_ws;
    int* cnt = (int*)w;                         // 256 B
    int* slot_of = (int*)(w + 256);             // 16 KB
    unsigned short* bufA = (unsigned short*)(w + 1048576ull);     // 32 MiB
    unsigned short* hbuf = (unsigned short*)(w + 34603008ull);    // 22 MiB
    float* dbuf = (float*)(w + 57671680ull);    // 64 MiB -> ends ~125 MiB

    hipMemsetAsync(cnt, 0, 256, stream);

    k_route<<<RROWS, 256, 0, stream>>>(flat_h, flat_idx, cnt, slot_of, bufA);
    k_gemm1<<<8 * 11 * 8, 256, 0, stream>>>(bufA, gw, uw, cnt, hbuf);
    k_gemm2<<<8 * 16 * 8, 256, 0, stream>>>(hbuf, dwn, cnt, dbuf);
    k_combine<<<M_TOK, 256, 0, stream>>>(dbuf, slot_of, flat_gate, out);
}

// Round 3
// 461.401 us; speedup vs baseline: 1.1519x; 1.1519x over previous
//
#include <hip/hip_runtime.h>
#include <hip/hip_bf16.h>

#define M_TOK 2048
#define KDIM 2048
#define NDIM 1408
#define NEXP 8
#define RROWS (M_TOK * 2)
#define CAP 1024

typedef __attribute__((ext_vector_type(8))) short short8;
typedef __attribute__((ext_vector_type(4))) float f32x4;

__device__ __forceinline__ unsigned short bf16rn(float f) {
    unsigned int u = __builtin_bit_cast(unsigned int, f);
    u += 0x7FFFu + ((u >> 16) & 1u);
    return (unsigned short)(u >> 16);
}
__device__ __forceinline__ unsigned int pk2(float a, float b) {
    return (unsigned int)bf16rn(a) | ((unsigned int)bf16rn(b) << 16);
}
// packed fp32x2 -> bf16x2 (RNE), compiler emits v_cvt_pk_bf16_f32
__device__ __forceinline__ unsigned int cvtpk(float a, float b) {
    __hip_bfloat162 h = __float22bfloat162_rn(make_float2(a, b));
    unsigned int u;
    __builtin_memcpy(&u, &h, 4);
    return u;
}

// async global->LDS, 16 B per lane; LDS dest wave-uniform base + lane*16
__device__ __forceinline__ void glds16(const void* g, void* l) {
    __builtin_amdgcn_global_load_lds(
        (const __attribute__((address_space(1))) unsigned int*)g,
        (__attribute__((address_space(3))) unsigned int*)l, 16, 0, 0);
}

// ---------------- routing + dispatch (fp32 -> bf16 row copy) ----------------
__global__ void k_route(const float* __restrict__ h, const int* __restrict__ idx,
                        int* __restrict__ cnt, int* __restrict__ slot_of,
                        unsigned short* __restrict__ bufA) {
    int r = blockIdx.x;
    __shared__ int s_ep;
    if (threadIdx.x == 0) {
        int e = idx[r];
        int p = atomicAdd(&cnt[e], 1);
        int ep = e * CAP + p;
        slot_of[r] = ep;
        s_ep = ep;
    }
    __syncthreads();
    int ep = s_ep;
    const float4* src = (const float4*)(h + (size_t)(r >> 1) * KDIM) + threadIdx.x * 2;
    float4 a = src[0], b = src[1];
    uint4 o;
    o.x = pk2(a.x, a.y); o.y = pk2(a.z, a.w);
    o.z = pk2(b.x, b.y); o.w = pk2(b.z, b.w);
    *((uint4*)(bufA + (size_t)ep * KDIM) + threadIdx.x) = o;
}

// ---------------- GEMM1: g,u = A @ W^T ; h = silu(min(g,10)) * clip(u) ------
// fp32 weights: coalesced reg-prefetch (1 K-step ahead) + swizzled ds_write.
// Per K-step: barrier; ds_write(current regs); issue glds16(A)+next wloads;
// barrier (single combined drain); MFMA.
__global__ __launch_bounds__(256, 2)
void k_gemm1(const unsigned short* __restrict__ bufA,
             const float* __restrict__ gw,
             const float* __restrict__ uw,
             const int* __restrict__ cnt, unsigned short* __restrict__ hbuf) {
    const int f = blockIdx.x;
    const int e = f & 7;
    const int t = f >> 3;            // 0..87
    const int n_blk = t % 11;
    const int m_blk = t / 11;        // 0..7
    const int m0 = m_blk * 128;
    if (m0 >= cnt[e]) return;
    const int n0 = n_blk * 128;

    const unsigned short* A = bufA + (size_t)e * CAP * KDIM;
    const float* G = gw + (size_t)e * NDIM * KDIM;
    const float* U = uw + (size_t)e * NDIM * KDIM;

    __shared__ unsigned short sA[128 * 64];
    __shared__ unsigned short sG[128 * 64];
    __shared__ unsigned short sU[128 * 64];

    const int tid = threadIdx.x;
    const int lane = tid & 63;
    const int wave = tid >> 6;
    const int wm = (wave >> 1) * 64, wn = (wave & 1) * 64;
    const int q = lane >> 4, l15 = lane & 15;
    // A DMA source swizzle: lane covers (row_in_seg = lane>>3, cb = (lane&7)^(row&7))
    const int sr = lane >> 3;
    const int scb = (lane & 7) ^ (sr & 7);
    const int xi = l15 & 7;                 // reader xor key
    const int cbl0 = (q ^ xi) * 8;          // kh=0 LDS col offset (shorts)
    const int cbl1 = ((4 + q) ^ xi) * 8;    // kh=1

    // coalesced weight staging: instr i covers rows i*16..i*16+15, 16 lanes
    // contiguous per row. thread -> (row_t = tid>>4, float4-col c4 = tid&15).
    const int row_t = tid >> 4;
    const int c4 = tid & 15;
    const float* Gb = G + (size_t)(n0 + row_t) * KDIM + c4 * 4;
    const float* Ub = U + (size_t)(n0 + row_t) * KDIM + c4 * 4;
    // LDS dest: row r = i*16+row_t; (r&7)==(row_t&7) so swizzle is i-invariant
    const int swz = (((c4 >> 1) ^ (row_t & 7)) << 3) + ((c4 & 1) << 2); // shorts
    unsigned short* wpG = &sG[row_t * 64 + swz];
    unsigned short* wpU = &sU[row_t * 64 + swz];

    f32x4 accG[4][4] = {};
    f32x4 accU[4][4] = {};

    // prologue: prefetch weights for k0 = 0
    float4 gv[8], uv[8];
#pragma unroll
    for (int i = 0; i < 8; i++) gv[i] = *(const float4*)(Gb + (size_t)i * 16 * KDIM);
#pragma unroll
    for (int i = 0; i < 8; i++) uv[i] = *(const float4*)(Ub + (size_t)i * 16 * KDIM);

    for (int k0 = 0; k0 < KDIM; k0 += 64) {
        __syncthreads();                    // prev MFMA done reading LDS
        // convert + swizzled store of THIS step's weights (regs already loaded)
#pragma unroll
        for (int i = 0; i < 8; i++) {
            uint2 o;
            o.x = cvtpk(gv[i].x, gv[i].y);
            o.y = cvtpk(gv[i].z, gv[i].w);
            *(uint2*)(wpG + i * 1024) = o;
        }
#pragma unroll
        for (int i = 0; i < 8; i++) {
            uint2 o;
            o.x = cvtpk(uv[i].x, uv[i].y);
            o.y = cvtpk(uv[i].z, uv[i].w);
            *(uint2*)(wpU + i * 1024) = o;
        }
        // issue A tile DMA + next-step weight loads (drain together at barrier)
#pragma unroll
        for (int c = 0; c < 4; c++) {
            int seg = wave * 4 + c;         // wave-uniform
            int row = seg * 8 + sr;
            glds16(A + (size_t)(m0 + row) * KDIM + k0 + scb * 8, &sA[seg * 512]);
        }
        if (k0 + 64 < KDIM) {
            const float* Gn = Gb + k0 + 64;
            const float* Un = Ub + k0 + 64;
#pragma unroll
            for (int i = 0; i < 8; i++) gv[i] = *(const float4*)(Gn + (size_t)i * 16 * KDIM);
#pragma unroll
            for (int i = 0; i < 8; i++) uv[i] = *(const float4*)(Un + (size_t)i * 16 * KDIM);
        }
        __syncthreads();                    // single combined vmem drain

#pragma unroll
        for (int kh = 0; kh < 2; kh++) {
            const int co = kh ? cbl1 : cbl0;
            short8 af[4], gf[4], uf[4];
#pragma unroll
            for (int i = 0; i < 4; i++) {
                af[i] = *(const short8*)&sA[(wm + i * 16 + l15) * 64 + co];
                gf[i] = *(const short8*)&sG[(wn + i * 16 + l15) * 64 + co];
                uf[i] = *(const short8*)&sU[(wn + i * 16 + l15) * 64 + co];
            }
#pragma unroll
            for (int i = 0; i < 4; i++)
#pragma unroll
                for (int j = 0; j < 4; j++) {
                    accG[i][j] = __builtin_amdgcn_mfma_f32_16x16x32_bf16(af[i], gf[j], accG[i][j], 0, 0, 0);
                    accU[i][j] = __builtin_amdgcn_mfma_f32_16x16x32_bf16(af[i], uf[j], accU[i][j], 0, 0, 0);
                }
        }
    }

    unsigned short* H = hbuf + (size_t)e * CAP * NDIM;
#pragma unroll
    for (int i = 0; i < 4; i++)
#pragma unroll
        for (int j = 0; j < 4; j++) {
            int col = n0 + wn + j * 16 + l15;
#pragma unroll
            for (int rg = 0; rg < 4; rg++) {
                int row = m0 + wm + i * 16 + q * 4 + rg;
                float g = accG[i][j][rg];
                float u = accU[i][j][rg];
                g = fminf(g, 10.f);
                u = fminf(fmaxf(u, -10.f), 10.f);
                float hv = g / (1.f + __expf(-g)) * u;
                H[(size_t)row * NDIM + col] = bf16rn(hv);
            }
        }
}

// ---------------- GEMM2: d = h @ dw^T -> dbuf (fp32, no atomics) ------------
// same restructure: coalesced weight prefetch + single combined drain.
__global__ __launch_bounds__(256, 2)
void k_gemm2(const unsigned short* __restrict__ hbuf,
             const float* __restrict__ dwn, const int* __restrict__ cnt,
             float* __restrict__ dbuf) {
    const int f = blockIdx.x;
    const int e = f & 7;
    const int t = f >> 3;            // 0..127
    const int n_blk = t & 15;
    const int m_blk = t >> 4;        // 0..7
    const int cnt_e = cnt[e];
    const int m0 = m_blk * 128;
    if (m0 >= cnt_e) return;
    const int n0 = n_blk * 128;      // over KDIM

    const unsigned short* A = hbuf + (size_t)e * CAP * NDIM;
    const float* B = dwn + (size_t)e * KDIM * NDIM;

    __shared__ unsigned short sA[128 * 64];
    __shared__ unsigned short sB[128 * 64];

    const int tid = threadIdx.x;
    const int lane = tid & 63;
    const int wave = tid >> 6;
    const int wm = (wave >> 1) * 64, wn = (wave & 1) * 64;
    const int q = lane >> 4, l15 = lane & 15;
    const int sr = lane >> 3;
    const int scb = (lane & 7) ^ (sr & 7);
    const int xi = l15 & 7;
    const int cbl0 = (q ^ xi) * 8;
    const int cbl1 = ((4 + q) ^ xi) * 8;

    const int row_t = tid >> 4;
    const int c4 = tid & 15;
    const float* Bb = B + (size_t)(n0 + row_t) * NDIM + c4 * 4;
    const int swz = (((c4 >> 1) ^ (row_t & 7)) << 3) + ((c4 & 1) << 2);
    unsigned short* wpB = &sB[row_t * 64 + swz];

    f32x4 acc[4][4] = {};

    float4 bv[8];
#pragma unroll
    for (int i = 0; i < 8; i++) bv[i] = *(const float4*)(Bb + (size_t)i * 16 * NDIM);

    for (int k0 = 0; k0 < NDIM; k0 += 64) {
        __syncthreads();
#pragma unroll
        for (int i = 0; i < 8; i++) {
            uint2 o;
            o.x = cvtpk(bv[i].x, bv[i].y);
            o.y = cvtpk(bv[i].z, bv[i].w);
            *(uint2*)(wpB + i * 1024) = o;
        }
#pragma unroll
        for (int c = 0; c < 4; c++) {
            int seg = wave * 4 + c;
            int row = seg * 8 + sr;
            glds16(A + (size_t)(m0 + row) * NDIM + k0 + scb * 8, &sA[seg * 512]);
        }
        if (k0 + 64 < NDIM) {
            const float* Bn = Bb + k0 + 64;
#pragma unroll
            for (int i = 0; i < 8; i++) bv[i] = *(const float4*)(Bn + (size_t)i * 16 * NDIM);
        }
        __syncthreads();

#pragma unroll
        for (int kh = 0; kh < 2; kh++) {
            const int co = kh ? cbl1 : cbl0;
            short8 af[4], bfr[4];
#pragma unroll
            for (int i = 0; i < 4; i++) {
                af[i] = *(const short8*)&sA[(wm + i * 16 + l15) * 64 + co];
                bfr[i] = *(const short8*)&sB[(wn + i * 16 + l15) * 64 + co];
            }
#pragma unroll
            for (int i = 0; i < 4; i++)
#pragma unroll
                for (int j = 0; j < 4; j++)
                    acc[i][j] = __builtin_amdgcn_mfma_f32_16x16x32_bf16(af[i], bfr[j], acc[i][j], 0, 0, 0);
        }
    }

    float* D = dbuf + (size_t)e * CAP * KDIM;
#pragma unroll
    for (int i = 0; i < 4; i++) {
#pragma unroll
        for (int rg = 0; rg < 4; rg++) {
            int row = m0 + wm + i * 16 + q * 4 + rg;
            if (row < cnt_e) {
                float* drow = D + (size_t)row * KDIM + n0 + wn + l15;
#pragma unroll
                for (int j = 0; j < 4; j++)
                    drow[j * 16] = acc[i][j][rg];
            }
        }
    }
}

// ---------------- combine: out[tok] = g0*d[slot0] + g1*d[slot1] -------------
__global__ void k_combine(const float* __restrict__ dbuf, const int* __restrict__ slot_of,
                          const float* __restrict__ gate, float* __restrict__ out) {
    int tk = blockIdx.x;
    int s0 = slot_of[2 * tk], s1 = slot_of[2 * tk + 1];
    float g0 = gate[2 * tk], g1 = gate[2 * tk + 1];
    const float4* r0 = (const float4*)(dbuf + (size_t)s0 * KDIM);
    const float4* r1 = (const float4*)(dbuf + (size_t)s1 * KDIM);
    float4* o = (float4*)(out + (size_t)tk * KDIM);
    int i = threadIdx.x * 2;
#pragma unroll
    for (int c = 0; c < 2; c++) {
        float4 a = r0[i + c], b = r1[i + c];
        float4 v;
        v.x = g0 * a.x + g1 * b.x;
        v.y = g0 * a.y + g1 * b.y;
        v.z = g0 * a.z + g1 * b.z;
        v.w = g0 * a.w + g1 * b.w;
        o[i + c] = v;
    }
}

extern "C" void kernel_launch(void* const* d_in, const int* in_sizes, int n_in,
                              void* d_out, int out_size, void* d_ws, size_t ws_size,
                              hipStream_t stream) {
    const float* flat_h = (const float*)d_in[0];
    const int* flat_idx = (const int*)d_in[1];
    const float* flat_gate = (const float*)d_in[2];
    const float* gw = (const float*)d_in[3];
    const float* uw = (const float*)d_in[4];
    const float* dwn = (const float*)d_in[5];
    float* out = (float*)d_out;

    char* w = (char*)d_ws;
    int* cnt = (int*)w;                         // 256 B
    int* slot_of = (int*)(w + 256);             // 16 KB
    unsigned short* bufA = (unsigned short*)(w + 1048576ull);     // 32 MiB
    unsigned short* hbuf = (unsigned short*)(w + 34603008ull);    // 22 MiB
    float* dbuf = (float*)(w + 57671680ull);    // 64 MiB -> ends ~125 MiB

    hipMemsetAsync(cnt, 0, 256, stream);

    k_route<<<RROWS, 256, 0, stream>>>(flat_h, flat_idx, cnt, slot_of, bufA);
    k_gemm1<<<8 * 11 * 8, 256, 0, stream>>>(bufA, gw, uw, cnt, hbuf);
    k_gemm2<<<8 * 16 * 8, 256, 0, stream>>>(hbuf, dwn, cnt, dbuf);
    k_combine<<<M_TOK, 256, 0, stream>>>(dbuf, slot_of, flat_gate, out);
}

// Round 4
// 431.902 us; speedup vs baseline: 1.2306x; 1.0683x over previous
//
#include <hip/hip_runtime.h>
#include <hip/hip_bf16.h>

#define M_TOK 2048
#define KDIM 2048
#define NDIM 1408
#define NEXP 8
#define RROWS (M_TOK * 2)
#define CAP 1024

typedef __attribute__((ext_vector_type(8))) short short8;
typedef __attribute__((ext_vector_type(4))) float f32x4;

__device__ __forceinline__ unsigned short bf16rn(float f) {
    unsigned int u = __builtin_bit_cast(unsigned int, f);
    u += 0x7FFFu + ((u >> 16) & 1u);
    return (unsigned short)(u >> 16);
}
__device__ __forceinline__ unsigned int pk2(float a, float b) {
    return (unsigned int)bf16rn(a) | ((unsigned int)bf16rn(b) << 16);
}
// packed fp32x2 -> bf16x2 (RNE), compiler emits v_cvt_pk_bf16_f32
__device__ __forceinline__ unsigned int cvtpk(float a, float b) {
    __hip_bfloat162 h = __float22bfloat162_rn(make_float2(a, b));
    unsigned int u;
    __builtin_memcpy(&u, &h, 4);
    return u;
}

// async global->LDS, 16 B per lane; LDS dest wave-uniform base + lane*16
__device__ __forceinline__ void glds16(const void* g, void* l) {
    __builtin_amdgcn_global_load_lds(
        (const __attribute__((address_space(1))) unsigned int*)g,
        (__attribute__((address_space(3))) unsigned int*)l, 16, 0, 0);
}

// ---------------- routing + dispatch (fp32 -> bf16 row copy) ----------------
__global__ void k_route(const float* __restrict__ h, const int* __restrict__ idx,
                        int* __restrict__ cnt, int* __restrict__ slot_of,
                        unsigned short* __restrict__ bufA) {
    int r = blockIdx.x;
    __shared__ int s_ep;
    if (threadIdx.x == 0) {
        int e = idx[r];
        int p = atomicAdd(&cnt[e], 1);
        int ep = e * CAP + p;
        slot_of[r] = ep;
        s_ep = ep;
    }
    __syncthreads();
    int ep = s_ep;
    const float4* src = (const float4*)(h + (size_t)(r >> 1) * KDIM) + threadIdx.x * 2;
    float4 a = src[0], b = src[1];
    uint4 o;
    o.x = pk2(a.x, a.y); o.y = pk2(a.z, a.w);
    o.z = pk2(b.x, b.y); o.w = pk2(b.z, b.w);
    *((uint4*)(bufA + (size_t)ep * KDIM) + threadIdx.x) = o;
}

// ---------------- GEMM1: g,u = A @ W^T ; h = silu(min(g,10)) * clip(u) ------
// Raw-barrier pipeline: only vmcnt(0) is at step top (loads issued last step
// have had the whole MFMA phase to land). sA double-buffered; sG/sU single.
__global__ __launch_bounds__(256, 2)
void k_gemm1(const unsigned short* __restrict__ bufA,
             const float* __restrict__ gw,
             const float* __restrict__ uw,
             const int* __restrict__ cnt, unsigned short* __restrict__ hbuf) {
    const int f = blockIdx.x;
    const int e = f & 7;
    const int t = f >> 3;            // 0..87
    const int n_blk = t % 11;
    const int m_blk = t / 11;        // 0..7
    const int m0 = m_blk * 128;
    if (m0 >= cnt[e]) return;
    const int n0 = n_blk * 128;

    const unsigned short* A = bufA + (size_t)e * CAP * KDIM;
    const float* G = gw + (size_t)e * NDIM * KDIM;
    const float* U = uw + (size_t)e * NDIM * KDIM;

    __shared__ unsigned short sA0[128 * 64];
    __shared__ unsigned short sA1[128 * 64];
    __shared__ unsigned short sG[128 * 64];
    __shared__ unsigned short sU[128 * 64];

    const int tid = threadIdx.x;
    const int lane = tid & 63;
    const int wave = tid >> 6;
    const int wm = (wave >> 1) * 64, wn = (wave & 1) * 64;
    const int q = lane >> 4, l15 = lane & 15;
    // A DMA source swizzle: lane covers (row_in_seg = lane>>3, cb = (lane&7)^(row&7))
    const int sr = lane >> 3;
    const int scb = (lane & 7) ^ (sr & 7);
    const int xi = l15 & 7;                 // reader xor key
    const int cbl0 = (q ^ xi) * 8;          // kh=0 LDS col offset (shorts)
    const int cbl1 = ((4 + q) ^ xi) * 8;    // kh=1

    // coalesced weight staging: instr i covers rows i*16..i*16+15, 16 lanes
    // contiguous per row. thread -> (row_t = tid>>4, float4-col c4 = tid&15).
    const int row_t = tid >> 4;
    const int c4 = tid & 15;
    const float* Gb = G + (size_t)(n0 + row_t) * KDIM + c4 * 4;
    const float* Ub = U + (size_t)(n0 + row_t) * KDIM + c4 * 4;
    // LDS dest: row r = i*16+row_t; (r&7)==(row_t&7) so swizzle is i-invariant
    const int swz = (((c4 >> 1) ^ (row_t & 7)) << 3) + ((c4 & 1) << 2); // shorts
    unsigned short* wpG = &sG[row_t * 64 + swz];
    unsigned short* wpU = &sU[row_t * 64 + swz];

    f32x4 accG[4][4] = {};
    f32x4 accU[4][4] = {};

    unsigned short* sAr = sA0;   // MFMA reads this
    unsigned short* sAw = sA1;   // DMA prefetch lands here

    // prologue: issue A(0) DMA into sA0 and weight loads for k=0
    float4 gv[8], uv[8];
#pragma unroll
    for (int c = 0; c < 4; c++) {
        int seg = wave * 4 + c;             // wave-uniform
        int row = seg * 8 + sr;
        glds16(A + (size_t)(m0 + row) * KDIM + scb * 8, &sA0[seg * 512]);
    }
#pragma unroll
    for (int i = 0; i < 8; i++) gv[i] = *(const float4*)(Gb + (size_t)i * 16 * KDIM);
#pragma unroll
    for (int i = 0; i < 8; i++) uv[i] = *(const float4*)(Ub + (size_t)i * 16 * KDIM);

    for (int k0 = 0; k0 < KDIM; k0 += 64) {
        __builtin_amdgcn_s_barrier();       // prev step's LDS reads complete
        asm volatile("s_waitcnt vmcnt(0)" ::: "memory");  // W(k) regs + A(k) DMA
        __builtin_amdgcn_sched_barrier(0);

        // convert + swizzled store of THIS step's weights
#pragma unroll
        for (int i = 0; i < 8; i++) {
            uint2 o;
            o.x = cvtpk(gv[i].x, gv[i].y);
            o.y = cvtpk(gv[i].z, gv[i].w);
            *(uint2*)(wpG + i * 1024) = o;
        }
#pragma unroll
        for (int i = 0; i < 8; i++) {
            uint2 o;
            o.x = cvtpk(uv[i].x, uv[i].y);
            o.y = cvtpk(uv[i].z, uv[i].w);
            *(uint2*)(wpU + i * 1024) = o;
        }

        // prefetch next step: A DMA into sAw + weight loads (fly across MFMA)
        if (k0 + 64 < KDIM) {
#pragma unroll
            for (int c = 0; c < 4; c++) {
                int seg = wave * 4 + c;
                int row = seg * 8 + sr;
                glds16(A + (size_t)(m0 + row) * KDIM + k0 + 64 + scb * 8, &sAw[seg * 512]);
            }
            const float* Gn = Gb + k0 + 64;
            const float* Un = Ub + k0 + 64;
#pragma unroll
            for (int i = 0; i < 8; i++) gv[i] = *(const float4*)(Gn + (size_t)i * 16 * KDIM);
#pragma unroll
            for (int i = 0; i < 8; i++) uv[i] = *(const float4*)(Un + (size_t)i * 16 * KDIM);
        }

        asm volatile("s_waitcnt lgkmcnt(0)" ::: "memory");  // ds_writes visible
        __builtin_amdgcn_sched_barrier(0);
        __builtin_amdgcn_s_barrier();       // NO vmem drain here

#pragma unroll
        for (int kh = 0; kh < 2; kh++) {
            const int co = kh ? cbl1 : cbl0;
            short8 af[4], gf[4], uf[4];
#pragma unroll
            for (int i = 0; i < 4; i++) {
                af[i] = *(const short8*)&sAr[(wm + i * 16 + l15) * 64 + co];
                gf[i] = *(const short8*)&sG[(wn + i * 16 + l15) * 64 + co];
                uf[i] = *(const short8*)&sU[(wn + i * 16 + l15) * 64 + co];
            }
#pragma unroll
            for (int i = 0; i < 4; i++)
#pragma unroll
                for (int j = 0; j < 4; j++) {
                    accG[i][j] = __builtin_amdgcn_mfma_f32_16x16x32_bf16(af[i], gf[j], accG[i][j], 0, 0, 0);
                    accU[i][j] = __builtin_amdgcn_mfma_f32_16x16x32_bf16(af[i], uf[j], accU[i][j], 0, 0, 0);
                }
        }

        unsigned short* tmp = sAr; sAr = sAw; sAw = tmp;
    }

    unsigned short* H = hbuf + (size_t)e * CAP * NDIM;
#pragma unroll
    for (int i = 0; i < 4; i++)
#pragma unroll
        for (int j = 0; j < 4; j++) {
            int col = n0 + wn + j * 16 + l15;
#pragma unroll
            for (int rg = 0; rg < 4; rg++) {
                int row = m0 + wm + i * 16 + q * 4 + rg;
                float g = accG[i][j][rg];
                float u = accU[i][j][rg];
                g = fminf(g, 10.f);
                u = fminf(fmaxf(u, -10.f), 10.f);
                float hv = g / (1.f + __expf(-g)) * u;
                H[(size_t)row * NDIM + col] = bf16rn(hv);
            }
        }
}

// ---------------- GEMM2: d = h @ dw^T -> dbuf (fp32, no atomics) ------------
// same raw-barrier pipeline.
__global__ __launch_bounds__(256, 2)
void k_gemm2(const unsigned short* __restrict__ hbuf,
             const float* __restrict__ dwn, const int* __restrict__ cnt,
             float* __restrict__ dbuf) {
    const int f = blockIdx.x;
    const int e = f & 7;
    const int t = f >> 3;            // 0..127
    const int n_blk = t & 15;
    const int m_blk = t >> 4;        // 0..7
    const int cnt_e = cnt[e];
    const int m0 = m_blk * 128;
    if (m0 >= cnt_e) return;
    const int n0 = n_blk * 128;      // over KDIM

    const unsigned short* A = hbuf + (size_t)e * CAP * NDIM;
    const float* B = dwn + (size_t)e * KDIM * NDIM;

    __shared__ unsigned short sA0[128 * 64];
    __shared__ unsigned short sA1[128 * 64];
    __shared__ unsigned short sB[128 * 64];

    const int tid = threadIdx.x;
    const int lane = tid & 63;
    const int wave = tid >> 6;
    const int wm = (wave >> 1) * 64, wn = (wave & 1) * 64;
    const int q = lane >> 4, l15 = lane & 15;
    const int sr = lane >> 3;
    const int scb = (lane & 7) ^ (sr & 7);
    const int xi = l15 & 7;
    const int cbl0 = (q ^ xi) * 8;
    const int cbl1 = ((4 + q) ^ xi) * 8;

    const int row_t = tid >> 4;
    const int c4 = tid & 15;
    const float* Bb = B + (size_t)(n0 + row_t) * NDIM + c4 * 4;
    const int swz = (((c4 >> 1) ^ (row_t & 7)) << 3) + ((c4 & 1) << 2);
    unsigned short* wpB = &sB[row_t * 64 + swz];

    f32x4 acc[4][4] = {};

    unsigned short* sAr = sA0;
    unsigned short* sAw = sA1;

    float4 bv[8];
#pragma unroll
    for (int c = 0; c < 4; c++) {
        int seg = wave * 4 + c;
        int row = seg * 8 + sr;
        glds16(A + (size_t)(m0 + row) * NDIM + scb * 8, &sA0[seg * 512]);
    }
#pragma unroll
    for (int i = 0; i < 8; i++) bv[i] = *(const float4*)(Bb + (size_t)i * 16 * NDIM);

    for (int k0 = 0; k0 < NDIM; k0 += 64) {
        __builtin_amdgcn_s_barrier();
        asm volatile("s_waitcnt vmcnt(0)" ::: "memory");
        __builtin_amdgcn_sched_barrier(0);

#pragma unroll
        for (int i = 0; i < 8; i++) {
            uint2 o;
            o.x = cvtpk(bv[i].x, bv[i].y);
            o.y = cvtpk(bv[i].z, bv[i].w);
            *(uint2*)(wpB + i * 1024) = o;
        }

        if (k0 + 64 < NDIM) {
#pragma unroll
            for (int c = 0; c < 4; c++) {
                int seg = wave * 4 + c;
                int row = seg * 8 + sr;
                glds16(A + (size_t)(m0 + row) * NDIM + k0 + 64 + scb * 8, &sAw[seg * 512]);
            }
            const float* Bn = Bb + k0 + 64;
#pragma unroll
            for (int i = 0; i < 8; i++) bv[i] = *(const float4*)(Bn + (size_t)i * 16 * NDIM);
        }

        asm volatile("s_waitcnt lgkmcnt(0)" ::: "memory");
        __builtin_amdgcn_sched_barrier(0);
        __builtin_amdgcn_s_barrier();

#pragma unroll
        for (int kh = 0; kh < 2; kh++) {
            const int co = kh ? cbl1 : cbl0;
            short8 af[4], bfr[4];
#pragma unroll
            for (int i = 0; i < 4; i++) {
                af[i] = *(const short8*)&sAr[(wm + i * 16 + l15) * 64 + co];
                bfr[i] = *(const short8*)&sB[(wn + i * 16 + l15) * 64 + co];
            }
#pragma unroll
            for (int i = 0; i < 4; i++)
#pragma unroll
                for (int j = 0; j < 4; j++)
                    acc[i][j] = __builtin_amdgcn_mfma_f32_16x16x32_bf16(af[i], bfr[j], acc[i][j], 0, 0, 0);
        }

        unsigned short* tmp = sAr; sAr = sAw; sAw = tmp;
    }

    float* D = dbuf + (size_t)e * CAP * KDIM;
#pragma unroll
    for (int i = 0; i < 4; i++) {
#pragma unroll
        for (int rg = 0; rg < 4; rg++) {
            int row = m0 + wm + i * 16 + q * 4 + rg;
            if (row < cnt_e) {
                float* drow = D + (size_t)row * KDIM + n0 + wn + l15;
#pragma unroll
                for (int j = 0; j < 4; j++)
                    drow[j * 16] = acc[i][j][rg];
            }
        }
    }
}

// ---------------- combine: out[tok] = g0*d[slot0] + g1*d[slot1] -------------
__global__ void k_combine(const float* __restrict__ dbuf, const int* __restrict__ slot_of,
                          const float* __restrict__ gate, float* __restrict__ out) {
    int tk = blockIdx.x;
    int s0 = slot_of[2 * tk], s1 = slot_of[2 * tk + 1];
    float g0 = gate[2 * tk], g1 = gate[2 * tk + 1];
    const float4* r0 = (const float4*)(dbuf + (size_t)s0 * KDIM);
    const float4* r1 = (const float4*)(dbuf + (size_t)s1 * KDIM);
    float4* o = (float4*)(out + (size_t)tk * KDIM);
    int i = threadIdx.x * 2;
#pragma unroll
    for (int c = 0; c < 2; c++) {
        float4 a = r0[i + c], b = r1[i + c];
        float4 v;
        v.x = g0 * a.x + g1 * b.x;
        v.y = g0 * a.y + g1 * b.y;
        v.z = g0 * a.z + g1 * b.z;
        v.w = g0 * a.w + g1 * b.w;
        o[i + c] = v;
    }
}

extern "C" void kernel_launch(void* const* d_in, const int* in_sizes, int n_in,
                              void* d_out, int out_size, void* d_ws, size_t ws_size,
                              hipStream_t stream) {
    const float* flat_h = (const float*)d_in[0];
    const int* flat_idx = (const int*)d_in[1];
    const float* flat_gate = (const float*)d_in[2];
    const float* gw = (const float*)d_in[3];
    const float* uw = (const float*)d_in[4];
    const float* dwn = (const float*)d_in[5];
    float* out = (float*)d_out;

    char* w = (char*)d_ws;
    int* cnt = (int*)w;                         // 256 B
    int* slot_of = (int*)(w + 256);             // 16 KB
    unsigned short* bufA = (unsigned short*)(w + 1048576ull);     // 32 MiB
    unsigned short* hbuf = (unsigned short*)(w + 34603008ull);    // 22 MiB
    float* dbuf = (float*)(w + 57671680ull);    // 64 MiB -> ends ~125 MiB

    hipMemsetAsync(cnt, 0, 256, stream);

    k_route<<<RROWS, 256, 0, stream>>>(flat_h, flat_idx, cnt, slot_of, bufA);
    k_gemm1<<<8 * 11 * 8, 256, 0, stream>>>(bufA, gw, uw, cnt, hbuf);
    k_gemm2<<<8 * 16 * 8, 256, 0, stream>>>(hbuf, dwn, cnt, dbuf);
    k_combine<<<M_TOK, 256, 0, stream>>>(dbuf, slot_of, flat_gate, out);
}